// Round 7
// baseline (193.804 us; speedup 1.0000x reference)
//
#include <hip/hip_runtime.h>
#include <math.h>

#define S_LEN 2048
#define C_DIM 512
#define NH 16
#define HD 32
#define PLANE_U (NH * S_LEN * HD)   // 1,048,576 ushorts = 2MB per plane

typedef __attribute__((ext_vector_type(8))) short bf16x8;
typedef __attribute__((ext_vector_type(8))) unsigned short u16x8;
typedef __attribute__((ext_vector_type(4))) float f32x4;

__device__ __forceinline__ unsigned short f2b(float f) {
    unsigned int x = __float_as_uint(f);
    unsigned int r = (x + 0x7FFFu + ((x >> 16) & 1u)) >> 16;   // RNE
    return (unsigned short)r;
}

// split x into bf16 hi (truncated) + bf16 lo (RNE of residual): hi+lo ~ 2^-17 rel
__device__ __forceinline__ void cvt_hilo(float x, unsigned short& hi, unsigned short& lo) {
    unsigned int b = __float_as_uint(x);
    hi = (unsigned short)(b >> 16);
    float hif = __uint_as_float(b & 0xFFFF0000u);
    lo = f2b(x - hif);
}

// ---------------- projection: complex GEMM via bf16 MFMA, hi/lo split ------
// z<2 (q,k): D = W·X^T (rows=o, cols=s) -> store ushort4 along d in [h][s][d]
// z==2 (v):  D = X·W^T (rows=s, cols=o) -> store ushort4 along s in [h][d][s]
#define PROW 40   // padded LDS row stride in ushorts (80B, 16B-aligned)

__global__ __launch_bounds__(256)
void proj_mfma(const float* __restrict__ Q, const float* __restrict__ V,
               const float* __restrict__ K,
               const float* __restrict__ Wq, const float* __restrict__ bq,
               const float* __restrict__ Wk, const float* __restrict__ bk,
               const float* __restrict__ Wv, const float* __restrict__ bv,
               unsigned short* __restrict__ ws)
{
    const int z = blockIdx.z;
    const float *X, *W, *b;
    if (z == 0)      { X = Q; W = Wq; b = bq; }
    else if (z == 1) { X = K; W = Wk; b = bk; }
    else             { X = V; W = Wv; b = bv; }

    const int s0 = blockIdx.x * 64;
    const int o0 = blockIdx.y * 64;

    const float2 *Asrc, *Bsrc; int arow0, brow0;
    if (z < 2) { Asrc = (const float2*)W; arow0 = o0; Bsrc = (const float2*)X; brow0 = s0; }
    else       { Asrc = (const float2*)X; arow0 = s0; Bsrc = (const float2*)W; brow0 = o0; }

    __shared__ __align__(16) unsigned short LArh[64*PROW], LArl[64*PROW];
    __shared__ __align__(16) unsigned short LAih[64*PROW], LAil[64*PROW];
    __shared__ __align__(16) unsigned short LBrh[64*PROW], LBrl[64*PROW];
    __shared__ __align__(16) unsigned short LBih[64*PROW], LBil[64*PROW];

    const int t    = threadIdx.x;
    const int wave = t >> 6;
    const int lr   = t & 15;
    const int g    = (t & 63) >> 4;
    const int srow = t >> 2;        // staging row 0..63
    const int sk8  = (t & 3) * 8;   // staging k chunk (8 complex)

    const f32x4 zf = {0.f,0.f,0.f,0.f};
    f32x4 accR[4], accI[4];
    #pragma unroll
    for (int i = 0; i < 4; ++i) { accR[i] = zf; accI[i] = zf; }

    for (int k0 = 0; k0 < C_DIM; k0 += 32) {
        __syncthreads();
        // ---- stage A tile ----
        {
            const float4* s4 = (const float4*)(Asrc + (size_t)(arow0 + srow)*C_DIM + k0 + sk8);
            float4 f0 = s4[0], f1 = s4[1], f2v = s4[2], f3 = s4[3];
            float re[8] = {f0.x,f0.z,f1.x,f1.z,f2v.x,f2v.z,f3.x,f3.z};
            float im[8] = {f0.y,f0.w,f1.y,f1.w,f2v.y,f2v.w,f3.y,f3.w};
            u16x8 rh, rl, ih, il;
            #pragma unroll
            for (int j = 0; j < 8; ++j) {
                unsigned short h_, l_;
                cvt_hilo(re[j], h_, l_); rh[j] = h_; rl[j] = l_;
                cvt_hilo(im[j], h_, l_); ih[j] = h_; il[j] = l_;
            }
            int wb = srow*PROW + sk8;
            *(u16x8*)&LArh[wb] = rh; *(u16x8*)&LArl[wb] = rl;
            *(u16x8*)&LAih[wb] = ih; *(u16x8*)&LAil[wb] = il;
        }
        // ---- stage B tile ----
        {
            const float4* s4 = (const float4*)(Bsrc + (size_t)(brow0 + srow)*C_DIM + k0 + sk8);
            float4 f0 = s4[0], f1 = s4[1], f2v = s4[2], f3 = s4[3];
            float re[8] = {f0.x,f0.z,f1.x,f1.z,f2v.x,f2v.z,f3.x,f3.z};
            float im[8] = {f0.y,f0.w,f1.y,f1.w,f2v.y,f2v.w,f3.y,f3.w};
            u16x8 rh, rl, ih, il;
            #pragma unroll
            for (int j = 0; j < 8; ++j) {
                unsigned short h_, l_;
                cvt_hilo(re[j], h_, l_); rh[j] = h_; rl[j] = l_;
                cvt_hilo(im[j], h_, l_); ih[j] = h_; il[j] = l_;
            }
            int wb = srow*PROW + sk8;
            *(u16x8*)&LBrh[wb] = rh; *(u16x8*)&LBrl[wb] = rl;
            *(u16x8*)&LBih[wb] = ih; *(u16x8*)&LBil[wb] = il;
        }
        __syncthreads();

        // ---- A fragments (wave's 16 rows) ----
        const int ab = (wave*16 + lr)*PROW + g*8;
        bf16x8 aRH = *(const bf16x8*)&LArh[ab];
        bf16x8 aRL = *(const bf16x8*)&LArl[ab];
        bf16x8 aIH = *(const bf16x8*)&LAih[ab];
        bf16x8 aIL = *(const bf16x8*)&LAil[ab];
        bf16x8 aIHn, aILn;
        #pragma unroll
        for (int j = 0; j < 8; ++j) { aIHn[j] = aIH[j] ^ (short)0x8000; aILn[j] = aIL[j] ^ (short)0x8000; }

        #pragma unroll
        for (int tile = 0; tile < 4; ++tile) {
            const int bb = (tile*16 + lr)*PROW + g*8;
            bf16x8 bRH = *(const bf16x8*)&LBrh[bb];
            bf16x8 bRL = *(const bf16x8*)&LBrl[bb];
            bf16x8 bIH = *(const bf16x8*)&LBih[bb];
            bf16x8 bIL = *(const bf16x8*)&LBil[bb];
            // Re: aR*bR - aI*bI (hi*hi + hi*lo + lo*hi)
            accR[tile] = __builtin_amdgcn_mfma_f32_16x16x32_bf16(aRH,  bRH, accR[tile], 0,0,0);
            accR[tile] = __builtin_amdgcn_mfma_f32_16x16x32_bf16(aRL,  bRH, accR[tile], 0,0,0);
            accR[tile] = __builtin_amdgcn_mfma_f32_16x16x32_bf16(aRH,  bRL, accR[tile], 0,0,0);
            accR[tile] = __builtin_amdgcn_mfma_f32_16x16x32_bf16(aIHn, bIH, accR[tile], 0,0,0);
            accR[tile] = __builtin_amdgcn_mfma_f32_16x16x32_bf16(aILn, bIH, accR[tile], 0,0,0);
            accR[tile] = __builtin_amdgcn_mfma_f32_16x16x32_bf16(aIHn, bIL, accR[tile], 0,0,0);
            // Im: aR*bI + aI*bR
            accI[tile] = __builtin_amdgcn_mfma_f32_16x16x32_bf16(aRH,  bIH, accI[tile], 0,0,0);
            accI[tile] = __builtin_amdgcn_mfma_f32_16x16x32_bf16(aRL,  bIH, accI[tile], 0,0,0);
            accI[tile] = __builtin_amdgcn_mfma_f32_16x16x32_bf16(aRH,  bIL, accI[tile], 0,0,0);
            accI[tile] = __builtin_amdgcn_mfma_f32_16x16x32_bf16(aIH,  bRH, accI[tile], 0,0,0);
            accI[tile] = __builtin_amdgcn_mfma_f32_16x16x32_bf16(aIL,  bRH, accI[tile], 0,0,0);
            accI[tile] = __builtin_amdgcn_mfma_f32_16x16x32_bf16(aIH,  bRL, accI[tile], 0,0,0);
        }
    }

    // ---- epilogue ----
    const float2* b2 = (const float2*)b;
    if (z < 2) {
        unsigned short* pr = ws + (z == 0 ? 0 : 2) * (size_t)PLANE_U;
        unsigned short* pi = pr + PLANE_U;
        const int obase = o0 + wave*16 + g*4;
        const int h = obase >> 5, d0 = obase & 31;
        float bR[4], bI[4];
        #pragma unroll
        for (int r = 0; r < 4; ++r) { float2 bb = b2[obase + r]; bR[r] = bb.x; bI[r] = bb.y; }
        #pragma unroll
        for (int tile = 0; tile < 4; ++tile) {
            int s = s0 + tile*16 + lr;
            size_t idx = ((size_t)h*S_LEN + s)*HD + d0;
            ushort4 pkR, pkI;
            pkR.x = f2b(accR[tile][0]+bR[0]); pkR.y = f2b(accR[tile][1]+bR[1]);
            pkR.z = f2b(accR[tile][2]+bR[2]); pkR.w = f2b(accR[tile][3]+bR[3]);
            pkI.x = f2b(accI[tile][0]+bI[0]); pkI.y = f2b(accI[tile][1]+bI[1]);
            pkI.z = f2b(accI[tile][2]+bI[2]); pkI.w = f2b(accI[tile][3]+bI[3]);
            *(ushort4*)&pr[idx] = pkR;
            *(ushort4*)&pi[idx] = pkI;
        }
    } else {
        unsigned short* tr = ws + 4 * (size_t)PLANE_U;
        unsigned short* ti = tr + PLANE_U;
        const int sbase = s0 + wave*16 + g*4;
        #pragma unroll
        for (int tile = 0; tile < 4; ++tile) {
            int o = o0 + tile*16 + lr;
            int h = o >> 5, d = o & 31;
            float2 bb = b2[o];
            size_t idx = ((size_t)h*HD + d)*S_LEN + sbase;
            ushort4 pkR, pkI;
            pkR.x = f2b(accR[tile][0]+bb.x); pkR.y = f2b(accR[tile][1]+bb.x);
            pkR.z = f2b(accR[tile][2]+bb.x); pkR.w = f2b(accR[tile][3]+bb.x);
            pkI.x = f2b(accI[tile][0]+bb.y); pkI.y = f2b(accI[tile][1]+bb.y);
            pkI.z = f2b(accI[tile][2]+bb.y); pkI.w = f2b(accI[tile][3]+bb.y);
            *(ushort4*)&tr[idx] = pkR;
            *(ushort4*)&ti[idx] = pkI;
        }
    }
}

// ---------------- MFMA flash attention, block-cooperative split-K --------
// SWAPPED QK^T (D[key][q], col=q=lr) + REGISTER-LOCAL PV: lane (g,lr) holds
// P for keys t*16+g*4+r of q-row lr. PV uses those directly as a half-K
// A-fragment: A[row=lr][k=g*8+j] = p[j] for j<4, 0 for j>=4; B duplicates a
// 4-key (8B) slice of V^T into both halves (the dup half hits A's zeros).
// => NO LDS in the main loop: no write->read dependency, no bank conflicts.
// Partials purely additive (no max tracking; |s|<=~15 so exp can't overflow).
// launch_bounds min-waves stays 4: 8 caps at 32 VGPR and spills (round 4).
#define RED_F2 (8*16*32)          // 4096 float2 = 32KB partial-O region

__global__ __launch_bounds__(512, 4)
void attn_mfma(const unsigned short* __restrict__ ws, float* __restrict__ out)
{
    const int bid   = blockIdx.x;
    const int h     = bid & (NH - 1);   // bid%8 = head%8 -> per-XCD KV locality
    const int strip = bid >> 4;         // 0..127
    const int wave  = threadIdx.x >> 6; // 0..7 -> k-range owner
    const int lr    = threadIdx.x & 15;
    const int g     = (threadIdx.x & 63) >> 4;

    const unsigned short* qr  = ws + 0*(size_t)PLANE_U + (size_t)h*S_LEN*HD;
    const unsigned short* qi  = ws + 1*(size_t)PLANE_U + (size_t)h*S_LEN*HD;
    const unsigned short* kr  = ws + 2*(size_t)PLANE_U + (size_t)h*S_LEN*HD;
    const unsigned short* ki  = ws + 3*(size_t)PLANE_U + (size_t)h*S_LEN*HD;
    const unsigned short* vtr = ws + 4*(size_t)PLANE_U + (size_t)h*HD*S_LEN;
    const unsigned short* vti = ws + 5*(size_t)PLANE_U + (size_t)h*HD*S_LEN;

    const int q0 = strip * 16;

    // Q fragments (B-operand): lane supplies Q[q=lr][k=g*8+j]
    bf16x8 bQr = *(const bf16x8*)&qr[(size_t)(q0 + lr)*HD + g*8];
    bf16x8 bQi = *(const bf16x8*)&qi[(size_t)(q0 + lr)*HD + g*8];
    bf16x8 bQrn;
    #pragma unroll
    for (int j = 0; j < 8; ++j) bQrn[j] = bQr[j] ^ (short)0x8000;

    // LDS only for the end-of-kernel block combine.
    __shared__ __align__(16) char smem[RED_F2*8 + 8*16*4];

    const f32x4 zf = {0.f, 0.f, 0.f, 0.f};
    f32x4 accO[2][2];
    #pragma unroll
    for (int dt = 0; dt < 2; ++dt) { accO[dt][0] = zf; accO[dt][1] = zf; }
    float l_lane = 0.f;   // partial denom for q=lr (this lane's row slice)

    const int kbeg = wave * 256;
    const float sc2 = 1.0f / 32.0f;
    for (int k0 = kbeg; k0 < kbeg + 256; k0 += 64) {
        // ---- per 16-key subtile: 4 QK mfma -> softmax -> 4 PV mfma ----
        #pragma unroll
        for (int t = 0; t < 4; ++t) {
            const size_t krow = (size_t)(k0 + t*16 + lr)*HD + g*8;
            bf16x8 aKr = *(const bf16x8*)&kr[krow];
            bf16x8 aKi = *(const bf16x8*)&ki[krow];
            // D[key][q]: re = kr.qr + ki.qi ; im = kr.qi + ki.(-qr)
            f32x4 sR = __builtin_amdgcn_mfma_f32_16x16x32_bf16(aKi, bQi,  zf, 0, 0, 0);
            sR       = __builtin_amdgcn_mfma_f32_16x16x32_bf16(aKr, bQr,  sR, 0, 0, 0);
            f32x4 sI = __builtin_amdgcn_mfma_f32_16x16x32_bf16(aKi, bQrn, zf, 0, 0, 0);
            sI       = __builtin_amdgcn_mfma_f32_16x16x32_bf16(aKr, bQi,  sI, 0, 0, 0);
            // lane holds S[key = t*16 + g*4 + r][q = lr], r=0..3
            float p[4];
            #pragma unroll
            for (int r = 0; r < 4; ++r) {
                p[r] = __expf(__builtin_amdgcn_sqrtf(
                    fmaf(sR[r], sR[r], sI[r]*sI[r]) * sc2));
                l_lane += p[r];
            }
            // A-frag: keys in low K-half (k = g*8 + j, j<4), zeros above.
            bf16x8 aP;
            aP[0] = (short)f2b(p[0]); aP[1] = (short)f2b(p[1]);
            aP[2] = (short)f2b(p[2]); aP[3] = (short)f2b(p[3]);
            aP[4] = 0; aP[5] = 0; aP[6] = 0; aP[7] = 0;
            // B-frag: V^T[d = dt*16+lr][key = k0+t*16+g*4 .. +3], 8B load
            // duplicated into both K-halves (upper half multiplies zeros).
            const size_t vbase = (size_t)k0 + t*16 + g*4;
            #pragma unroll
            for (int dt = 0; dt < 2; ++dt) {
                const size_t voff = (size_t)(dt*16 + lr)*S_LEN + vbase;
                uint2 vrw = *(const uint2*)&vtr[voff];
                uint2 viw = *(const uint2*)&vti[voff];
                bf16x8 bVr, bVi;
                *(uint2*)&bVr = vrw; *((uint2*)&bVr + 1) = vrw;
                *(uint2*)&bVi = viw; *((uint2*)&bVi + 1) = viw;
                accO[dt][0] = __builtin_amdgcn_mfma_f32_16x16x32_bf16(aP, bVr, accO[dt][0], 0, 0, 0);
                accO[dt][1] = __builtin_amdgcn_mfma_f32_16x16x32_bf16(aP, bVi, accO[dt][1], 0, 0, 0);
            }
        }
    }

    // ---- wave l-reduction: q=lr slices live at lanes lr, lr+16, lr+32, lr+48
    l_lane += __shfl_xor(l_lane, 16);
    l_lane += __shfl_xor(l_lane, 32);

    // ---- block combine in LDS ----
    __syncthreads();
    float2* red  = (float2*)smem;                 // [8][16][32] complex partials
    float*  lred = (float*)(smem + RED_F2*8);     // [8][16]
    #pragma unroll
    for (int r = 0; r < 4; ++r) {
        int q = g*4 + r;
        #pragma unroll
        for (int dt = 0; dt < 2; ++dt) {
            int d = dt*16 + lr;
            red[wave*512 + q*32 + d] = make_float2(accO[dt][0][r], accO[dt][1][r]);
        }
    }
    if (g == 0) lred[wave*16 + lr] = l_lane;      // l for q=lr
    __syncthreads();

    // thread i sums partials for output element (q = i>>5, d = i&31)
    {
        const int i = threadIdx.x;
        const int q = i >> 5, d = i & 31;
        float sr = 0.f, si = 0.f, sl = 0.f;
        #pragma unroll
        for (int w = 0; w < 8; ++w) {
            float2 v = red[w*512 + q*32 + d];
            sr += v.x; si += v.y;
            sl += lred[w*16 + q];
        }
        float inv = 1.0f / sl;
        float2* o2 = (float2*)out;
        o2[(size_t)(q0 + q)*C_DIM + h*HD + d] = make_float2(sr*inv, si*inv);
    }
}

extern "C" void kernel_launch(void* const* d_in, const int* in_sizes, int n_in,
                              void* d_out, int out_size, void* d_ws, size_t ws_size,
                              hipStream_t stream)
{
    const float* Q  = (const float*)d_in[0];
    const float* V  = (const float*)d_in[1];
    const float* K  = (const float*)d_in[2];
    const float* Wq = (const float*)d_in[3];
    const float* bq = (const float*)d_in[4];
    const float* Wk = (const float*)d_in[5];
    const float* bk = (const float*)d_in[6];
    const float* Wv = (const float*)d_in[7];
    const float* bv = (const float*)d_in[8];
    unsigned short* ws = (unsigned short*)d_ws;   // 6 planes * 2MB = 12MB
    float* out = (float*)d_out;

    dim3 gp(S_LEN/64, C_DIM/64, 3);
    proj_mfma<<<gp, 256, 0, stream>>>(Q, V, K, Wq, bq, Wk, bk, Wv, bv, ws);

    attn_mfma<<<dim3(128*NH), 512, 0, stream>>>(ws, out);
}

// Round 8
// 193.716 us; speedup vs baseline: 1.0005x; 1.0005x over previous
//
#include <hip/hip_runtime.h>
#include <math.h>

#define S_LEN 2048
#define C_DIM 512
#define NH 16
#define HD 32
#define PLANE_U (NH * S_LEN * HD)   // 1,048,576 ushorts = 2MB per plane

typedef __attribute__((ext_vector_type(8))) short bf16x8;
typedef __attribute__((ext_vector_type(8))) unsigned short u16x8;
typedef __attribute__((ext_vector_type(4))) float f32x4;

__device__ __forceinline__ unsigned short f2b(float f) {
    unsigned int x = __float_as_uint(f);
    unsigned int r = (x + 0x7FFFu + ((x >> 16) & 1u)) >> 16;   // RNE
    return (unsigned short)r;
}

// split x into bf16 hi (truncated) + bf16 lo (RNE of residual): hi+lo ~ 2^-17 rel
__device__ __forceinline__ void cvt_hilo(float x, unsigned short& hi, unsigned short& lo) {
    unsigned int b = __float_as_uint(x);
    hi = (unsigned short)(b >> 16);
    float hif = __uint_as_float(b & 0xFFFF0000u);
    lo = f2b(x - hif);
}

// ---------------- projection: complex GEMM via bf16 MFMA, hi/lo split ------
// z<2 (q,k): D = W·X^T (rows=o, cols=s) -> store ushort4 along d in [h][s][d]
// z==2 (v):  D = X·W^T (rows=s, cols=o) -> store ushort4 along s in [h][d][s]
#define PROW 40   // padded LDS row stride in ushorts (80B, 16B-aligned)

__global__ __launch_bounds__(256)
void proj_mfma(const float* __restrict__ Q, const float* __restrict__ V,
               const float* __restrict__ K,
               const float* __restrict__ Wq, const float* __restrict__ bq,
               const float* __restrict__ Wk, const float* __restrict__ bk,
               const float* __restrict__ Wv, const float* __restrict__ bv,
               unsigned short* __restrict__ ws)
{
    const int z = blockIdx.z;
    const float *X, *W, *b;
    if (z == 0)      { X = Q; W = Wq; b = bq; }
    else if (z == 1) { X = K; W = Wk; b = bk; }
    else             { X = V; W = Wv; b = bv; }

    const int s0 = blockIdx.x * 64;
    const int o0 = blockIdx.y * 64;

    const float2 *Asrc, *Bsrc; int arow0, brow0;
    if (z < 2) { Asrc = (const float2*)W; arow0 = o0; Bsrc = (const float2*)X; brow0 = s0; }
    else       { Asrc = (const float2*)X; arow0 = s0; Bsrc = (const float2*)W; brow0 = o0; }

    __shared__ __align__(16) unsigned short LArh[64*PROW], LArl[64*PROW];
    __shared__ __align__(16) unsigned short LAih[64*PROW], LAil[64*PROW];
    __shared__ __align__(16) unsigned short LBrh[64*PROW], LBrl[64*PROW];
    __shared__ __align__(16) unsigned short LBih[64*PROW], LBil[64*PROW];

    const int t    = threadIdx.x;
    const int wave = t >> 6;
    const int lr   = t & 15;
    const int g    = (t & 63) >> 4;
    const int srow = t >> 2;        // staging row 0..63
    const int sk8  = (t & 3) * 8;   // staging k chunk (8 complex)

    const f32x4 zf = {0.f,0.f,0.f,0.f};
    f32x4 accR[4], accI[4];
    #pragma unroll
    for (int i = 0; i < 4; ++i) { accR[i] = zf; accI[i] = zf; }

    for (int k0 = 0; k0 < C_DIM; k0 += 32) {
        __syncthreads();
        // ---- stage A tile ----
        {
            const float4* s4 = (const float4*)(Asrc + (size_t)(arow0 + srow)*C_DIM + k0 + sk8);
            float4 f0 = s4[0], f1 = s4[1], f2v = s4[2], f3 = s4[3];
            float re[8] = {f0.x,f0.z,f1.x,f1.z,f2v.x,f2v.z,f3.x,f3.z};
            float im[8] = {f0.y,f0.w,f1.y,f1.w,f2v.y,f2v.w,f3.y,f3.w};
            u16x8 rh, rl, ih, il;
            #pragma unroll
            for (int j = 0; j < 8; ++j) {
                unsigned short h_, l_;
                cvt_hilo(re[j], h_, l_); rh[j] = h_; rl[j] = l_;
                cvt_hilo(im[j], h_, l_); ih[j] = h_; il[j] = l_;
            }
            int wb = srow*PROW + sk8;
            *(u16x8*)&LArh[wb] = rh; *(u16x8*)&LArl[wb] = rl;
            *(u16x8*)&LAih[wb] = ih; *(u16x8*)&LAil[wb] = il;
        }
        // ---- stage B tile ----
        {
            const float4* s4 = (const float4*)(Bsrc + (size_t)(brow0 + srow)*C_DIM + k0 + sk8);
            float4 f0 = s4[0], f1 = s4[1], f2v = s4[2], f3 = s4[3];
            float re[8] = {f0.x,f0.z,f1.x,f1.z,f2v.x,f2v.z,f3.x,f3.z};
            float im[8] = {f0.y,f0.w,f1.y,f1.w,f2v.y,f2v.w,f3.y,f3.w};
            u16x8 rh, rl, ih, il;
            #pragma unroll
            for (int j = 0; j < 8; ++j) {
                unsigned short h_, l_;
                cvt_hilo(re[j], h_, l_); rh[j] = h_; rl[j] = l_;
                cvt_hilo(im[j], h_, l_); ih[j] = h_; il[j] = l_;
            }
            int wb = srow*PROW + sk8;
            *(u16x8*)&LBrh[wb] = rh; *(u16x8*)&LBrl[wb] = rl;
            *(u16x8*)&LBih[wb] = ih; *(u16x8*)&LBil[wb] = il;
        }
        __syncthreads();

        // ---- A fragments (wave's 16 rows) ----
        const int ab = (wave*16 + lr)*PROW + g*8;
        bf16x8 aRH = *(const bf16x8*)&LArh[ab];
        bf16x8 aRL = *(const bf16x8*)&LArl[ab];
        bf16x8 aIH = *(const bf16x8*)&LAih[ab];
        bf16x8 aIL = *(const bf16x8*)&LAil[ab];
        bf16x8 aIHn, aILn;
        #pragma unroll
        for (int j = 0; j < 8; ++j) { aIHn[j] = aIH[j] ^ (short)0x8000; aILn[j] = aIL[j] ^ (short)0x8000; }

        #pragma unroll
        for (int tile = 0; tile < 4; ++tile) {
            const int bb = (tile*16 + lr)*PROW + g*8;
            bf16x8 bRH = *(const bf16x8*)&LBrh[bb];
            bf16x8 bRL = *(const bf16x8*)&LBrl[bb];
            bf16x8 bIH = *(const bf16x8*)&LBih[bb];
            bf16x8 bIL = *(const bf16x8*)&LBil[bb];
            // Re: aR*bR - aI*bI (hi*hi + hi*lo + lo*hi)
            accR[tile] = __builtin_amdgcn_mfma_f32_16x16x32_bf16(aRH,  bRH, accR[tile], 0,0,0);
            accR[tile] = __builtin_amdgcn_mfma_f32_16x16x32_bf16(aRL,  bRH, accR[tile], 0,0,0);
            accR[tile] = __builtin_amdgcn_mfma_f32_16x16x32_bf16(aRH,  bRL, accR[tile], 0,0,0);
            accR[tile] = __builtin_amdgcn_mfma_f32_16x16x32_bf16(aIHn, bIH, accR[tile], 0,0,0);
            accR[tile] = __builtin_amdgcn_mfma_f32_16x16x32_bf16(aILn, bIH, accR[tile], 0,0,0);
            accR[tile] = __builtin_amdgcn_mfma_f32_16x16x32_bf16(aIHn, bIL, accR[tile], 0,0,0);
            // Im: aR*bI + aI*bR
            accI[tile] = __builtin_amdgcn_mfma_f32_16x16x32_bf16(aRH,  bIH, accI[tile], 0,0,0);
            accI[tile] = __builtin_amdgcn_mfma_f32_16x16x32_bf16(aRL,  bIH, accI[tile], 0,0,0);
            accI[tile] = __builtin_amdgcn_mfma_f32_16x16x32_bf16(aRH,  bIL, accI[tile], 0,0,0);
            accI[tile] = __builtin_amdgcn_mfma_f32_16x16x32_bf16(aIH,  bRH, accI[tile], 0,0,0);
            accI[tile] = __builtin_amdgcn_mfma_f32_16x16x32_bf16(aIL,  bRH, accI[tile], 0,0,0);
            accI[tile] = __builtin_amdgcn_mfma_f32_16x16x32_bf16(aIH,  bRL, accI[tile], 0,0,0);
        }
    }

    // ---- epilogue ----
    const float2* b2 = (const float2*)b;
    if (z < 2) {
        unsigned short* pr = ws + (z == 0 ? 0 : 2) * (size_t)PLANE_U;
        unsigned short* pi = pr + PLANE_U;
        const int obase = o0 + wave*16 + g*4;
        const int h = obase >> 5, d0 = obase & 31;
        float bR[4], bI[4];
        #pragma unroll
        for (int r = 0; r < 4; ++r) { float2 bb = b2[obase + r]; bR[r] = bb.x; bI[r] = bb.y; }
        #pragma unroll
        for (int tile = 0; tile < 4; ++tile) {
            int s = s0 + tile*16 + lr;
            size_t idx = ((size_t)h*S_LEN + s)*HD + d0;
            ushort4 pkR, pkI;
            pkR.x = f2b(accR[tile][0]+bR[0]); pkR.y = f2b(accR[tile][1]+bR[1]);
            pkR.z = f2b(accR[tile][2]+bR[2]); pkR.w = f2b(accR[tile][3]+bR[3]);
            pkI.x = f2b(accI[tile][0]+bI[0]); pkI.y = f2b(accI[tile][1]+bI[1]);
            pkI.z = f2b(accI[tile][2]+bI[2]); pkI.w = f2b(accI[tile][3]+bI[3]);
            *(ushort4*)&pr[idx] = pkR;
            *(ushort4*)&pi[idx] = pkI;
        }
    } else {
        unsigned short* tr = ws + 4 * (size_t)PLANE_U;
        unsigned short* ti = tr + PLANE_U;
        const int sbase = s0 + wave*16 + g*4;
        #pragma unroll
        for (int tile = 0; tile < 4; ++tile) {
            int o = o0 + tile*16 + lr;
            int h = o >> 5, d = o & 31;
            float2 bb = b2[o];
            size_t idx = ((size_t)h*HD + d)*S_LEN + sbase;
            ushort4 pkR, pkI;
            pkR.x = f2b(accR[tile][0]+bb.x); pkR.y = f2b(accR[tile][1]+bb.x);
            pkR.z = f2b(accR[tile][2]+bb.x); pkR.w = f2b(accR[tile][3]+bb.x);
            pkI.x = f2b(accI[tile][0]+bb.y); pkI.y = f2b(accI[tile][1]+bb.y);
            pkI.z = f2b(accI[tile][2]+bb.y); pkI.w = f2b(accI[tile][3]+bb.y);
            *(ushort4*)&tr[idx] = pkR;
            *(ushort4*)&ti[idx] = pkI;
        }
    }
}

// ---------------- MFMA flash attention, block-cooperative split-K --------
// SWAPPED QK^T (D[key][q], col=q=lr) + REGISTER-LOCAL full-K PV: lane (g,lr)
// computes P for keys {base+g*4..+3} of two 16-key subtiles (a,b) and packs
// both into ONE K=32 A-fragment (slots g*8+0..3 = subtile a, g*8+4..7 =
// subtile b). B-fragment = two 8B V^T slices (keys a-group | b-group) in
// matching halves. Per 64-key tile: 16 QK + 8 PV mfma (same count as the
// LDS version) with NO LDS round-trip, no bank conflicts, and only 2
// dependent PV mfma per accumulator. Partials purely additive (no max
// tracking; |s| <= ~15 so exp can't overflow; softmax shift-invariant).
// launch_bounds min-waves stays 4: 8 caps at 32 VGPR and spills (round 4).
#define RED_F2 (8*16*32)          // 4096 float2 = 32KB partial-O region

__global__ __launch_bounds__(512, 4)
void attn_mfma(const unsigned short* __restrict__ ws, float* __restrict__ out)
{
    const int bid   = blockIdx.x;
    const int h     = bid & (NH - 1);   // bid%8 = head%8 -> per-XCD KV locality
    const int strip = bid >> 4;         // 0..127
    const int wave  = threadIdx.x >> 6; // 0..7 -> k-range owner
    const int lr    = threadIdx.x & 15;
    const int g     = (threadIdx.x & 63) >> 4;

    const unsigned short* qr  = ws + 0*(size_t)PLANE_U + (size_t)h*S_LEN*HD;
    const unsigned short* qi  = ws + 1*(size_t)PLANE_U + (size_t)h*S_LEN*HD;
    const unsigned short* kr  = ws + 2*(size_t)PLANE_U + (size_t)h*S_LEN*HD;
    const unsigned short* ki  = ws + 3*(size_t)PLANE_U + (size_t)h*S_LEN*HD;
    const unsigned short* vtr = ws + 4*(size_t)PLANE_U + (size_t)h*HD*S_LEN;
    const unsigned short* vti = ws + 5*(size_t)PLANE_U + (size_t)h*HD*S_LEN;

    const int q0 = strip * 16;

    // Q fragments (B-operand): lane supplies Q[q=lr][k=g*8+j]
    bf16x8 bQr = *(const bf16x8*)&qr[(size_t)(q0 + lr)*HD + g*8];
    bf16x8 bQi = *(const bf16x8*)&qi[(size_t)(q0 + lr)*HD + g*8];
    bf16x8 bQrn;
    #pragma unroll
    for (int j = 0; j < 8; ++j) bQrn[j] = bQr[j] ^ (short)0x8000;

    // LDS only for the end-of-kernel block combine.
    __shared__ __align__(16) char smem[RED_F2*8 + 8*16*4];

    const f32x4 zf = {0.f, 0.f, 0.f, 0.f};
    f32x4 accO[2][2];
    #pragma unroll
    for (int dt = 0; dt < 2; ++dt) { accO[dt][0] = zf; accO[dt][1] = zf; }
    float l_lane = 0.f;   // partial denom for q=lr (this lane's row slice)

    const int kbeg = wave * 256;
    const float sc2 = 1.0f / 32.0f;
    for (int k0 = kbeg; k0 < kbeg + 256; k0 += 64) {
        // ---- per 32-key PAIR of subtiles: 8 QK mfma -> softmax -> 4 PV ----
        #pragma unroll
        for (int tp = 0; tp < 2; ++tp) {
            const int base = k0 + tp*32;    // subtile a = base, b = base+16
            float p[8];
            #pragma unroll
            for (int u = 0; u < 2; ++u) {
                const size_t krow = (size_t)(base + u*16 + lr)*HD + g*8;
                bf16x8 aKr = *(const bf16x8*)&kr[krow];
                bf16x8 aKi = *(const bf16x8*)&ki[krow];
                // D[key][q]: re = kr.qr + ki.qi ; im = kr.qi + ki.(-qr)
                f32x4 sR = __builtin_amdgcn_mfma_f32_16x16x32_bf16(aKi, bQi,  zf, 0, 0, 0);
                sR       = __builtin_amdgcn_mfma_f32_16x16x32_bf16(aKr, bQr,  sR, 0, 0, 0);
                f32x4 sI = __builtin_amdgcn_mfma_f32_16x16x32_bf16(aKi, bQrn, zf, 0, 0, 0);
                sI       = __builtin_amdgcn_mfma_f32_16x16x32_bf16(aKr, bQi,  sI, 0, 0, 0);
                // lane holds S[key = base + u*16 + g*4 + r][q = lr]
                #pragma unroll
                for (int r = 0; r < 4; ++r) {
                    float v = __expf(__builtin_amdgcn_sqrtf(
                        fmaf(sR[r], sR[r], sI[r]*sI[r]) * sc2));
                    p[u*4 + r] = v;
                    l_lane += v;
                }
            }
            // A-frag: slots g*8+0..3 = subtile a keys, g*8+4..7 = subtile b.
            bf16x8 aP;
            #pragma unroll
            for (int j = 0; j < 8; ++j) aP[j] = (short)f2b(p[j]);
            // B-frag: low half = V^T keys base+g*4..+3, high = base+16+g*4..+3
            const size_t vba = (size_t)base + g*4;
            #pragma unroll
            for (int dt = 0; dt < 2; ++dt) {
                const size_t vrow = (size_t)(dt*16 + lr)*S_LEN + vba;
                bf16x8 bVr, bVi;
                *(uint2*)&bVr       = *(const uint2*)&vtr[vrow];
                *((uint2*)&bVr + 1) = *(const uint2*)&vtr[vrow + 16];
                *(uint2*)&bVi       = *(const uint2*)&vti[vrow];
                *((uint2*)&bVi + 1) = *(const uint2*)&vti[vrow + 16];
                accO[dt][0] = __builtin_amdgcn_mfma_f32_16x16x32_bf16(aP, bVr, accO[dt][0], 0, 0, 0);
                accO[dt][1] = __builtin_amdgcn_mfma_f32_16x16x32_bf16(aP, bVi, accO[dt][1], 0, 0, 0);
            }
        }
    }

    // ---- wave l-reduction: q=lr slices live at lanes lr, lr+16, lr+32, lr+48
    l_lane += __shfl_xor(l_lane, 16);
    l_lane += __shfl_xor(l_lane, 32);

    // ---- block combine in LDS ----
    __syncthreads();
    float2* red  = (float2*)smem;                 // [8][16][32] complex partials
    float*  lred = (float*)(smem + RED_F2*8);     // [8][16]
    #pragma unroll
    for (int r = 0; r < 4; ++r) {
        int q = g*4 + r;
        #pragma unroll
        for (int dt = 0; dt < 2; ++dt) {
            int d = dt*16 + lr;
            red[wave*512 + q*32 + d] = make_float2(accO[dt][0][r], accO[dt][1][r]);
        }
    }
    if (g == 0) lred[wave*16 + lr] = l_lane;      // l for q=lr
    __syncthreads();

    // thread i sums partials for output element (q = i>>5, d = i&31)
    {
        const int i = threadIdx.x;
        const int q = i >> 5, d = i & 31;
        float sr = 0.f, si = 0.f, sl = 0.f;
        #pragma unroll
        for (int w = 0; w < 8; ++w) {
            float2 v = red[w*512 + q*32 + d];
            sr += v.x; si += v.y;
            sl += lred[w*16 + q];
        }
        float inv = 1.0f / sl;
        float2* o2 = (float2*)out;
        o2[(size_t)(q0 + q)*C_DIM + h*HD + d] = make_float2(sr*inv, si*inv);
    }
}

extern "C" void kernel_launch(void* const* d_in, const int* in_sizes, int n_in,
                              void* d_out, int out_size, void* d_ws, size_t ws_size,
                              hipStream_t stream)
{
    const float* Q  = (const float*)d_in[0];
    const float* V  = (const float*)d_in[1];
    const float* K  = (const float*)d_in[2];
    const float* Wq = (const float*)d_in[3];
    const float* bq = (const float*)d_in[4];
    const float* Wk = (const float*)d_in[5];
    const float* bk = (const float*)d_in[6];
    const float* Wv = (const float*)d_in[7];
    const float* bv = (const float*)d_in[8];
    unsigned short* ws = (unsigned short*)d_ws;   // 6 planes * 2MB = 12MB
    float* out = (float*)d_out;

    dim3 gp(S_LEN/64, C_DIM/64, 3);
    proj_mfma<<<gp, 256, 0, stream>>>(Q, V, K, Wq, bq, Wk, bk, Wv, bv, ws);

    attn_mfma<<<dim3(128*NH), 512, 0, stream>>>(ws, out);
}

// Round 9
// 104.363 us; speedup vs baseline: 1.8570x; 1.8562x over previous
//
#include <hip/hip_runtime.h>
#include <math.h>

#define S_LEN 2048
#define C_DIM 512
#define NH 16
#define HD 32
#define PLANE_U (NH * S_LEN * HD)   // 1,048,576 ushorts = 2MB per plane

typedef __attribute__((ext_vector_type(8))) short bf16x8;
typedef __attribute__((ext_vector_type(8))) unsigned short u16x8;
typedef __attribute__((ext_vector_type(4))) float f32x4;

__device__ __forceinline__ unsigned short f2b(float f) {
    unsigned int x = __float_as_uint(f);
    unsigned int r = (x + 0x7FFFu + ((x >> 16) & 1u)) >> 16;   // RNE
    return (unsigned short)r;
}

// split x into bf16 hi (truncated) + bf16 lo (RNE of residual): hi+lo ~ 2^-17 rel
__device__ __forceinline__ void cvt_hilo(float x, unsigned short& hi, unsigned short& lo) {
    unsigned int b = __float_as_uint(x);
    hi = (unsigned short)(b >> 16);
    float hif = __uint_as_float(b & 0xFFFF0000u);
    lo = f2b(x - hif);
}

// ---------------- projection: complex GEMM via bf16 MFMA, hi/lo split ------
// z<2 (q,k): D = W·X^T (rows=o, cols=s) -> store ushort4 along d in [h][s][d]
// z==2 (v):  D = X·W^T (rows=s, cols=o) -> store ushort4 along s in [h][d][s],
//            with the key axis PERMUTED within each 32-group: position
//            pos = u*16+g*4+r  ->  column c = g*8+u*4+r, so that attn's
//            swapped-PV B-fragment (P, register-resident) lines up with a
//            contiguous 16B A-fragment read of V^T.
#define PROW 40   // padded LDS row stride in ushorts (80B, 16B-aligned)

__global__ __launch_bounds__(256)
void proj_mfma(const float* __restrict__ Q, const float* __restrict__ V,
               const float* __restrict__ K,
               const float* __restrict__ Wq, const float* __restrict__ bq,
               const float* __restrict__ Wk, const float* __restrict__ bk,
               const float* __restrict__ Wv, const float* __restrict__ bv,
               unsigned short* __restrict__ ws)
{
    const int z = blockIdx.z;
    const float *X, *W, *b;
    if (z == 0)      { X = Q; W = Wq; b = bq; }
    else if (z == 1) { X = K; W = Wk; b = bk; }
    else             { X = V; W = Wv; b = bv; }

    const int s0 = blockIdx.x * 64;
    const int o0 = blockIdx.y * 64;

    const float2 *Asrc, *Bsrc; int arow0, brow0;
    if (z < 2) { Asrc = (const float2*)W; arow0 = o0; Bsrc = (const float2*)X; brow0 = s0; }
    else       { Asrc = (const float2*)X; arow0 = s0; Bsrc = (const float2*)W; brow0 = o0; }

    __shared__ __align__(16) unsigned short LArh[64*PROW], LArl[64*PROW];
    __shared__ __align__(16) unsigned short LAih[64*PROW], LAil[64*PROW];
    __shared__ __align__(16) unsigned short LBrh[64*PROW], LBrl[64*PROW];
    __shared__ __align__(16) unsigned short LBih[64*PROW], LBil[64*PROW];

    const int t    = threadIdx.x;
    const int wave = t >> 6;
    const int lr   = t & 15;
    const int g    = (t & 63) >> 4;
    const int srow = t >> 2;        // staging row 0..63
    const int sk8  = (t & 3) * 8;   // staging k chunk (8 complex)

    const f32x4 zf = {0.f,0.f,0.f,0.f};
    f32x4 accR[4], accI[4];
    #pragma unroll
    for (int i = 0; i < 4; ++i) { accR[i] = zf; accI[i] = zf; }

    for (int k0 = 0; k0 < C_DIM; k0 += 32) {
        __syncthreads();
        // ---- stage A tile ----
        {
            const float4* s4 = (const float4*)(Asrc + (size_t)(arow0 + srow)*C_DIM + k0 + sk8);
            float4 f0 = s4[0], f1 = s4[1], f2v = s4[2], f3 = s4[3];
            float re[8] = {f0.x,f0.z,f1.x,f1.z,f2v.x,f2v.z,f3.x,f3.z};
            float im[8] = {f0.y,f0.w,f1.y,f1.w,f2v.y,f2v.w,f3.y,f3.w};
            u16x8 rh, rl, ih, il;
            #pragma unroll
            for (int j = 0; j < 8; ++j) {
                unsigned short h_, l_;
                cvt_hilo(re[j], h_, l_); rh[j] = h_; rl[j] = l_;
                cvt_hilo(im[j], h_, l_); ih[j] = h_; il[j] = l_;
            }
            int wb = srow*PROW + sk8;
            *(u16x8*)&LArh[wb] = rh; *(u16x8*)&LArl[wb] = rl;
            *(u16x8*)&LAih[wb] = ih; *(u16x8*)&LAil[wb] = il;
        }
        // ---- stage B tile ----
        {
            const float4* s4 = (const float4*)(Bsrc + (size_t)(brow0 + srow)*C_DIM + k0 + sk8);
            float4 f0 = s4[0], f1 = s4[1], f2v = s4[2], f3 = s4[3];
            float re[8] = {f0.x,f0.z,f1.x,f1.z,f2v.x,f2v.z,f3.x,f3.z};
            float im[8] = {f0.y,f0.w,f1.y,f1.w,f2v.y,f2v.w,f3.y,f3.w};
            u16x8 rh, rl, ih, il;
            #pragma unroll
            for (int j = 0; j < 8; ++j) {
                unsigned short h_, l_;
                cvt_hilo(re[j], h_, l_); rh[j] = h_; rl[j] = l_;
                cvt_hilo(im[j], h_, l_); ih[j] = h_; il[j] = l_;
            }
            int wb = srow*PROW + sk8;
            *(u16x8*)&LBrh[wb] = rh; *(u16x8*)&LBrl[wb] = rl;
            *(u16x8*)&LBih[wb] = ih; *(u16x8*)&LBil[wb] = il;
        }
        __syncthreads();

        // ---- A fragments (wave's 16 rows) ----
        const int ab = (wave*16 + lr)*PROW + g*8;
        bf16x8 aRH = *(const bf16x8*)&LArh[ab];
        bf16x8 aRL = *(const bf16x8*)&LArl[ab];
        bf16x8 aIH = *(const bf16x8*)&LAih[ab];
        bf16x8 aIL = *(const bf16x8*)&LAil[ab];
        bf16x8 aIHn, aILn;
        #pragma unroll
        for (int j = 0; j < 8; ++j) { aIHn[j] = aIH[j] ^ (short)0x8000; aILn[j] = aIL[j] ^ (short)0x8000; }

        #pragma unroll
        for (int tile = 0; tile < 4; ++tile) {
            const int bb = (tile*16 + lr)*PROW + g*8;
            bf16x8 bRH = *(const bf16x8*)&LBrh[bb];
            bf16x8 bRL = *(const bf16x8*)&LBrl[bb];
            bf16x8 bIH = *(const bf16x8*)&LBih[bb];
            bf16x8 bIL = *(const bf16x8*)&LBil[bb];
            // Re: aR*bR - aI*bI (hi*hi + hi*lo + lo*hi)
            accR[tile] = __builtin_amdgcn_mfma_f32_16x16x32_bf16(aRH,  bRH, accR[tile], 0,0,0);
            accR[tile] = __builtin_amdgcn_mfma_f32_16x16x32_bf16(aRL,  bRH, accR[tile], 0,0,0);
            accR[tile] = __builtin_amdgcn_mfma_f32_16x16x32_bf16(aRH,  bRL, accR[tile], 0,0,0);
            accR[tile] = __builtin_amdgcn_mfma_f32_16x16x32_bf16(aIHn, bIH, accR[tile], 0,0,0);
            accR[tile] = __builtin_amdgcn_mfma_f32_16x16x32_bf16(aILn, bIH, accR[tile], 0,0,0);
            accR[tile] = __builtin_amdgcn_mfma_f32_16x16x32_bf16(aIHn, bIL, accR[tile], 0,0,0);
            // Im: aR*bI + aI*bR
            accI[tile] = __builtin_amdgcn_mfma_f32_16x16x32_bf16(aRH,  bIH, accI[tile], 0,0,0);
            accI[tile] = __builtin_amdgcn_mfma_f32_16x16x32_bf16(aRL,  bIH, accI[tile], 0,0,0);
            accI[tile] = __builtin_amdgcn_mfma_f32_16x16x32_bf16(aRH,  bIL, accI[tile], 0,0,0);
            accI[tile] = __builtin_amdgcn_mfma_f32_16x16x32_bf16(aIH,  bRH, accI[tile], 0,0,0);
            accI[tile] = __builtin_amdgcn_mfma_f32_16x16x32_bf16(aIL,  bRH, accI[tile], 0,0,0);
            accI[tile] = __builtin_amdgcn_mfma_f32_16x16x32_bf16(aIH,  bRL, accI[tile], 0,0,0);
        }
    }

    // ---- epilogue ----
    const float2* b2 = (const float2*)b;
    if (z < 2) {
        unsigned short* pr = ws + (z == 0 ? 0 : 2) * (size_t)PLANE_U;
        unsigned short* pi = pr + PLANE_U;
        const int obase = o0 + wave*16 + g*4;
        const int h = obase >> 5, d0 = obase & 31;
        float bR[4], bI[4];
        #pragma unroll
        for (int r = 0; r < 4; ++r) { float2 bb = b2[obase + r]; bR[r] = bb.x; bI[r] = bb.y; }
        #pragma unroll
        for (int tile = 0; tile < 4; ++tile) {
            int s = s0 + tile*16 + lr;
            size_t idx = ((size_t)h*S_LEN + s)*HD + d0;
            ushort4 pkR, pkI;
            pkR.x = f2b(accR[tile][0]+bR[0]); pkR.y = f2b(accR[tile][1]+bR[1]);
            pkR.z = f2b(accR[tile][2]+bR[2]); pkR.w = f2b(accR[tile][3]+bR[3]);
            pkI.x = f2b(accI[tile][0]+bI[0]); pkI.y = f2b(accI[tile][1]+bI[1]);
            pkI.z = f2b(accI[tile][2]+bI[2]); pkI.w = f2b(accI[tile][3]+bI[3]);
            *(ushort4*)&pr[idx] = pkR;
            *(ushort4*)&pi[idx] = pkI;
        }
    } else {
        unsigned short* tr = ws + 4 * (size_t)PLANE_U;
        unsigned short* ti = tr + PLANE_U;
        // key s = s0 + wave*16 + g*4 + r  ->  permuted column
        // c = s0 + (wave>>1)*32 + g*8 + (wave&1)*4 + r  (bijective in [0,64))
        const int cbase = s0 + (wave >> 1)*32 + g*8 + (wave & 1)*4;
        #pragma unroll
        for (int tile = 0; tile < 4; ++tile) {
            int o = o0 + tile*16 + lr;
            int h = o >> 5, d = o & 31;
            float2 bb = b2[o];
            size_t idx = ((size_t)h*HD + d)*S_LEN + cbase;
            ushort4 pkR, pkI;
            pkR.x = f2b(accR[tile][0]+bb.x); pkR.y = f2b(accR[tile][1]+bb.x);
            pkR.z = f2b(accR[tile][2]+bb.x); pkR.w = f2b(accR[tile][3]+bb.x);
            pkI.x = f2b(accI[tile][0]+bb.y); pkI.y = f2b(accI[tile][1]+bb.y);
            pkI.z = f2b(accI[tile][2]+bb.y); pkI.w = f2b(accI[tile][3]+bb.y);
            *(ushort4*)&tr[idx] = pkR;
            *(ushort4*)&ti[idx] = pkI;
        }
    }
}

// ---------------- MFMA flash attention, split-K + 2 q-strips/wave --------
// Swapped QK^T: S = mfma(K,Q) -> lane (g,lr) holds S[key=u*16+g*4+r][q=lr].
// Swapped PV:   O^T = mfma(V^T, P): A = V^T (16B contiguous, c-permuted
// plane), B = P packed in-register (lane supplies B[k=g*8+j][q=lr] =
// p[j] in compute order thanks to the proj-side column permutation).
// NO LDS in the main loop. Each wave processes TWO q-strips (shares K and
// V fragments -> 2x ILP, half the L2 KV traffic). Partials purely additive
// (no max tracking; |s| <= ~15). min-waves stays 4 (8 spilled, round 4).
#define RED_F2 (8*16*32)          // 4096 float2 = 32KB partial-O region

__global__ __launch_bounds__(512, 4)
void attn_mfma(const unsigned short* __restrict__ ws, float* __restrict__ out)
{
    const int bid   = blockIdx.x;       // 64 pairs x 16 heads
    const int h     = bid & (NH - 1);   // bid%8 = head%8 -> per-XCD KV locality
    const int pair  = bid >> 4;         // 0..63
    const int wave  = threadIdx.x >> 6; // 0..7 -> k-range owner
    const int lr    = threadIdx.x & 15;
    const int g     = (threadIdx.x & 63) >> 4;

    const unsigned short* qr  = ws + 0*(size_t)PLANE_U + (size_t)h*S_LEN*HD;
    const unsigned short* qi  = ws + 1*(size_t)PLANE_U + (size_t)h*S_LEN*HD;
    const unsigned short* kr  = ws + 2*(size_t)PLANE_U + (size_t)h*S_LEN*HD;
    const unsigned short* ki  = ws + 3*(size_t)PLANE_U + (size_t)h*S_LEN*HD;
    const unsigned short* vtr = ws + 4*(size_t)PLANE_U + (size_t)h*HD*S_LEN;
    const unsigned short* vti = ws + 5*(size_t)PLANE_U + (size_t)h*HD*S_LEN;

    const int qA = pair * 32;           // strip A rows qA..qA+15
    const int qB = qA + 16;             // strip B rows qB..qB+15

    // Q fragments (B-operand of QK): lane supplies Q[q=lr][k=g*8+j]
    bf16x8 bQrA = *(const bf16x8*)&qr[(size_t)(qA + lr)*HD + g*8];
    bf16x8 bQiA = *(const bf16x8*)&qi[(size_t)(qA + lr)*HD + g*8];
    bf16x8 bQrB = *(const bf16x8*)&qr[(size_t)(qB + lr)*HD + g*8];
    bf16x8 bQiB = *(const bf16x8*)&qi[(size_t)(qB + lr)*HD + g*8];
    bf16x8 bQrnA, bQrnB;
    #pragma unroll
    for (int j = 0; j < 8; ++j) {
        bQrnA[j] = bQrA[j] ^ (short)0x8000;
        bQrnB[j] = bQrB[j] ^ (short)0x8000;
    }

    // LDS only for the end-of-kernel block combine.
    __shared__ __align__(16) char smem[RED_F2*8 + 8*16*4];

    const f32x4 zf = {0.f, 0.f, 0.f, 0.f};
    f32x4 accA[2][2], accB[2][2];       // [d-tile][0=real,1=imag]
    #pragma unroll
    for (int dt = 0; dt < 2; ++dt) {
        accA[dt][0] = zf; accA[dt][1] = zf;
        accB[dt][0] = zf; accB[dt][1] = zf;
    }
    float lA = 0.f, lB = 0.f;           // denom partials for q=lr

    const int kbeg = wave * 256;
    const float sc2 = 1.0f / 32.0f;
    #pragma unroll 2
    for (int k0 = kbeg; k0 < kbeg + 256; k0 += 32) {
        // ---- one 32-key group: 16 QK mfma (2 strips) -> softmax -> 8 PV --
        bf16x8 bPA, bPB;                // P packed as PV B-fragments
        #pragma unroll
        for (int u = 0; u < 2; ++u) {
            const size_t krow = (size_t)(k0 + u*16 + lr)*HD + g*8;
            bf16x8 aKr = *(const bf16x8*)&kr[krow];
            bf16x8 aKi = *(const bf16x8*)&ki[krow];
            // strip A: re = kr.qr + ki.qi ; im = kr.qi + ki.(-qr)
            {
                f32x4 sR = __builtin_amdgcn_mfma_f32_16x16x32_bf16(aKi, bQiA,  zf, 0, 0, 0);
                sR       = __builtin_amdgcn_mfma_f32_16x16x32_bf16(aKr, bQrA,  sR, 0, 0, 0);
                f32x4 sI = __builtin_amdgcn_mfma_f32_16x16x32_bf16(aKi, bQrnA, zf, 0, 0, 0);
                sI       = __builtin_amdgcn_mfma_f32_16x16x32_bf16(aKr, bQiA,  sI, 0, 0, 0);
                #pragma unroll
                for (int r = 0; r < 4; ++r) {
                    float v = __expf(__builtin_amdgcn_sqrtf(
                        fmaf(sR[r], sR[r], sI[r]*sI[r]) * sc2));
                    bPA[u*4 + r] = (short)f2b(v);
                    lA += v;
                }
            }
            // strip B
            {
                f32x4 sR = __builtin_amdgcn_mfma_f32_16x16x32_bf16(aKi, bQiB,  zf, 0, 0, 0);
                sR       = __builtin_amdgcn_mfma_f32_16x16x32_bf16(aKr, bQrB,  sR, 0, 0, 0);
                f32x4 sI = __builtin_amdgcn_mfma_f32_16x16x32_bf16(aKi, bQrnB, zf, 0, 0, 0);
                sI       = __builtin_amdgcn_mfma_f32_16x16x32_bf16(aKr, bQiB,  sI, 0, 0, 0);
                #pragma unroll
                for (int r = 0; r < 4; ++r) {
                    float v = __expf(__builtin_amdgcn_sqrtf(
                        fmaf(sR[r], sR[r], sI[r]*sI[r]) * sc2));
                    bPB[u*4 + r] = (short)f2b(v);
                    lB += v;
                }
            }
        }
        // ---- PV: A = V^T (c-permuted plane, 16B loads), B = P in-register
        #pragma unroll
        for (int dt = 0; dt < 2; ++dt) {
            const size_t vrow = (size_t)(dt*16 + lr)*S_LEN + k0 + g*8;
            bf16x8 aVr = *(const bf16x8*)&vtr[vrow];
            bf16x8 aVi = *(const bf16x8*)&vti[vrow];
            accA[dt][0] = __builtin_amdgcn_mfma_f32_16x16x32_bf16(aVr, bPA, accA[dt][0], 0, 0, 0);
            accA[dt][1] = __builtin_amdgcn_mfma_f32_16x16x32_bf16(aVi, bPA, accA[dt][1], 0, 0, 0);
            accB[dt][0] = __builtin_amdgcn_mfma_f32_16x16x32_bf16(aVr, bPB, accB[dt][0], 0, 0, 0);
            accB[dt][1] = __builtin_amdgcn_mfma_f32_16x16x32_bf16(aVi, bPB, accB[dt][1], 0, 0, 0);
        }
    }

    // ---- wave l-reduction: q=lr slices live at lanes lr, lr+16, lr+32, lr+48
    lA += __shfl_xor(lA, 16); lA += __shfl_xor(lA, 32);
    lB += __shfl_xor(lB, 16); lB += __shfl_xor(lB, 32);

    // ---- block combine (strip A then strip B, same 32KB region) ----
    float2* red  = (float2*)smem;                 // [8][16][32] complex partials
    float*  lred = (float*)(smem + RED_F2*8);     // [8][16]
    float2* o2   = (float2*)out;

    #pragma unroll
    for (int strip = 0; strip < 2; ++strip) {
        __syncthreads();
        const f32x4 (*acc)[2] = strip ? accB : accA;
        const float  lval     = strip ? lB : lA;
        const int    qbase    = strip ? qB : qA;
        // PV D layout: lane (g,lr) holds O[q=lr][d = dt*16 + g*4 + r]
        #pragma unroll
        for (int dt = 0; dt < 2; ++dt)
            #pragma unroll
            for (int r = 0; r < 4; ++r)
                red[wave*512 + lr*32 + dt*16 + g*4 + r] =
                    make_float2(acc[dt][0][r], acc[dt][1][r]);
        if (g == 0) lred[wave*16 + lr] = lval;
        __syncthreads();
        // thread i sums partials for output element (q = i>>5, d = i&31)
        const int i = threadIdx.x;
        const int q = i >> 5, d = i & 31;
        float sr = 0.f, si = 0.f, sl = 0.f;
        #pragma unroll
        for (int w = 0; w < 8; ++w) {
            float2 v = red[w*512 + q*32 + d];
            sr += v.x; si += v.y;
            sl += lred[w*16 + q];
        }
        float inv = 1.0f / sl;
        o2[(size_t)(qbase + q)*C_DIM + h*HD + d] = make_float2(sr*inv, si*inv);
    }
}

extern "C" void kernel_launch(void* const* d_in, const int* in_sizes, int n_in,
                              void* d_out, int out_size, void* d_ws, size_t ws_size,
                              hipStream_t stream)
{
    const float* Q  = (const float*)d_in[0];
    const float* V  = (const float*)d_in[1];
    const float* K  = (const float*)d_in[2];
    const float* Wq = (const float*)d_in[3];
    const float* bq = (const float*)d_in[4];
    const float* Wk = (const float*)d_in[5];
    const float* bk = (const float*)d_in[6];
    const float* Wv = (const float*)d_in[7];
    const float* bv = (const float*)d_in[8];
    unsigned short* ws = (unsigned short*)d_ws;   // 6 planes * 2MB = 12MB
    float* out = (float*)d_out;

    dim3 gp(S_LEN/64, C_DIM/64, 3);
    proj_mfma<<<gp, 256, 0, stream>>>(Q, V, K, Wq, bq, Wk, bk, Wv, bv, ws);

    attn_mfma<<<dim3(64*NH), 512, 0, stream>>>(ws, out);
}

// Round 10
// 96.490 us; speedup vs baseline: 2.0085x; 1.0816x over previous
//
#include <hip/hip_runtime.h>
#include <math.h>

#define S_LEN 2048
#define C_DIM 512
#define NH 16
#define HD 32
#define PLANE_U (NH * S_LEN * HD)   // 1,048,576 ushorts = 2MB per plane

typedef __attribute__((ext_vector_type(8))) short bf16x8;
typedef __attribute__((ext_vector_type(8))) unsigned short u16x8;
typedef __attribute__((ext_vector_type(4))) float f32x4;

__device__ __forceinline__ unsigned short f2b(float f) {
    unsigned int x = __float_as_uint(f);
    unsigned int r = (x + 0x7FFFu + ((x >> 16) & 1u)) >> 16;   // RNE
    return (unsigned short)r;
}

// cheap split: hi = truncate(x), lo = truncate(x - hi). err(hi+lo) ~ 2^-17 rel
__device__ __forceinline__ void cvt_hilo(float x, unsigned short& hi, unsigned short& lo) {
    unsigned int b = __float_as_uint(x);
    hi = (unsigned short)(b >> 16);
    float hif = __uint_as_float(b & 0xFFFF0000u);
    lo = (unsigned short)(__float_as_uint(x - hif) >> 16);
}

// ---------------- projection: complex GEMM via bf16 MFMA ------------------
// z<2 (q,k): hi/lo split (12 mfma/tile-chunk), D = W·X^T -> [h][s][d]; the Q
//            plane is PRE-SCALED by 1/sqrt(32) (|c*s| = c*|s|, c>0).
// z==2 (v):  hi-only RNE (4 mfma/tile-chunk, err ~0.006), D = X·W^T -> V^T
//            plane [h][d][s] with key axis permuted within each 32-group
//            (pos u*16+g*4+r -> col g*8+u*4+r) to line up attn's swapped-PV
//            B-fragment with a contiguous 16B A-read.
#define PROW 40   // padded LDS row stride in ushorts (80B, 16B-aligned)

__global__ __launch_bounds__(256)
void proj_mfma(const float* __restrict__ Q, const float* __restrict__ V,
               const float* __restrict__ K,
               const float* __restrict__ Wq, const float* __restrict__ bq,
               const float* __restrict__ Wk, const float* __restrict__ bk,
               const float* __restrict__ Wv, const float* __restrict__ bv,
               unsigned short* __restrict__ ws)
{
    const int z = blockIdx.z;
    const float *X, *W, *b;
    if (z == 0)      { X = Q; W = Wq; b = bq; }
    else if (z == 1) { X = K; W = Wk; b = bk; }
    else             { X = V; W = Wv; b = bv; }
    const bool full = (z < 2);

    const int s0 = blockIdx.x * 64;
    const int o0 = blockIdx.y * 64;

    const float2 *Asrc, *Bsrc; int arow0, brow0;
    if (full) { Asrc = (const float2*)W; arow0 = o0; Bsrc = (const float2*)X; brow0 = s0; }
    else      { Asrc = (const float2*)X; arow0 = s0; Bsrc = (const float2*)W; brow0 = o0; }

    __shared__ __align__(16) unsigned short LArh[64*PROW], LArl[64*PROW];
    __shared__ __align__(16) unsigned short LAih[64*PROW], LAil[64*PROW];
    __shared__ __align__(16) unsigned short LBrh[64*PROW], LBrl[64*PROW];
    __shared__ __align__(16) unsigned short LBih[64*PROW], LBil[64*PROW];

    const int t    = threadIdx.x;
    const int wave = t >> 6;
    const int lr   = t & 15;
    const int g    = (t & 63) >> 4;
    const int srow = t >> 2;        // staging row 0..63
    const int sk8  = (t & 3) * 8;   // staging k chunk (8 complex)

    const f32x4 zf = {0.f,0.f,0.f,0.f};
    f32x4 accR[4], accI[4];
    #pragma unroll
    for (int i = 0; i < 4; ++i) { accR[i] = zf; accI[i] = zf; }

    for (int k0 = 0; k0 < C_DIM; k0 += 32) {
        __syncthreads();
        // ---- stage A tile ----
        {
            const float4* s4 = (const float4*)(Asrc + (size_t)(arow0 + srow)*C_DIM + k0 + sk8);
            float4 f0 = s4[0], f1 = s4[1], f2v = s4[2], f3 = s4[3];
            float re[8] = {f0.x,f0.z,f1.x,f1.z,f2v.x,f2v.z,f3.x,f3.z};
            float im[8] = {f0.y,f0.w,f1.y,f1.w,f2v.y,f2v.w,f3.y,f3.w};
            u16x8 rh, rl, ih, il;
            if (full) {
                #pragma unroll
                for (int j = 0; j < 8; ++j) {
                    unsigned short h_, l_;
                    cvt_hilo(re[j], h_, l_); rh[j] = h_; rl[j] = l_;
                    cvt_hilo(im[j], h_, l_); ih[j] = h_; il[j] = l_;
                }
            } else {
                #pragma unroll
                for (int j = 0; j < 8; ++j) { rh[j] = f2b(re[j]); ih[j] = f2b(im[j]); }
            }
            int wb = srow*PROW + sk8;
            *(u16x8*)&LArh[wb] = rh; *(u16x8*)&LAih[wb] = ih;
            if (full) { *(u16x8*)&LArl[wb] = rl; *(u16x8*)&LAil[wb] = il; }
        }
        // ---- stage B tile ----
        {
            const float4* s4 = (const float4*)(Bsrc + (size_t)(brow0 + srow)*C_DIM + k0 + sk8);
            float4 f0 = s4[0], f1 = s4[1], f2v = s4[2], f3 = s4[3];
            float re[8] = {f0.x,f0.z,f1.x,f1.z,f2v.x,f2v.z,f3.x,f3.z};
            float im[8] = {f0.y,f0.w,f1.y,f1.w,f2v.y,f2v.w,f3.y,f3.w};
            u16x8 rh, rl, ih, il;
            if (full) {
                #pragma unroll
                for (int j = 0; j < 8; ++j) {
                    unsigned short h_, l_;
                    cvt_hilo(re[j], h_, l_); rh[j] = h_; rl[j] = l_;
                    cvt_hilo(im[j], h_, l_); ih[j] = h_; il[j] = l_;
                }
            } else {
                #pragma unroll
                for (int j = 0; j < 8; ++j) { rh[j] = f2b(re[j]); ih[j] = f2b(im[j]); }
            }
            int wb = srow*PROW + sk8;
            *(u16x8*)&LBrh[wb] = rh; *(u16x8*)&LBih[wb] = ih;
            if (full) { *(u16x8*)&LBrl[wb] = rl; *(u16x8*)&LBil[wb] = il; }
        }
        __syncthreads();

        // ---- A fragments (wave's 16 rows) ----
        const int ab = (wave*16 + lr)*PROW + g*8;
        bf16x8 aRH = *(const bf16x8*)&LArh[ab];
        bf16x8 aIH = *(const bf16x8*)&LAih[ab];
        bf16x8 aIHn;
        #pragma unroll
        for (int j = 0; j < 8; ++j) aIHn[j] = aIH[j] ^ (short)0x8000;

        if (full) {
            bf16x8 aRL = *(const bf16x8*)&LArl[ab];
            bf16x8 aIL = *(const bf16x8*)&LAil[ab];
            bf16x8 aILn;
            #pragma unroll
            for (int j = 0; j < 8; ++j) aILn[j] = aIL[j] ^ (short)0x8000;

            #pragma unroll
            for (int tile = 0; tile < 4; ++tile) {
                const int bb = (tile*16 + lr)*PROW + g*8;
                bf16x8 bRH = *(const bf16x8*)&LBrh[bb];
                bf16x8 bRL = *(const bf16x8*)&LBrl[bb];
                bf16x8 bIH = *(const bf16x8*)&LBih[bb];
                bf16x8 bIL = *(const bf16x8*)&LBil[bb];
                accR[tile] = __builtin_amdgcn_mfma_f32_16x16x32_bf16(aRH,  bRH, accR[tile], 0,0,0);
                accR[tile] = __builtin_amdgcn_mfma_f32_16x16x32_bf16(aRL,  bRH, accR[tile], 0,0,0);
                accR[tile] = __builtin_amdgcn_mfma_f32_16x16x32_bf16(aRH,  bRL, accR[tile], 0,0,0);
                accR[tile] = __builtin_amdgcn_mfma_f32_16x16x32_bf16(aIHn, bIH, accR[tile], 0,0,0);
                accR[tile] = __builtin_amdgcn_mfma_f32_16x16x32_bf16(aILn, bIH, accR[tile], 0,0,0);
                accR[tile] = __builtin_amdgcn_mfma_f32_16x16x32_bf16(aIHn, bIL, accR[tile], 0,0,0);
                accI[tile] = __builtin_amdgcn_mfma_f32_16x16x32_bf16(aRH,  bIH, accI[tile], 0,0,0);
                accI[tile] = __builtin_amdgcn_mfma_f32_16x16x32_bf16(aRL,  bIH, accI[tile], 0,0,0);
                accI[tile] = __builtin_amdgcn_mfma_f32_16x16x32_bf16(aRH,  bIL, accI[tile], 0,0,0);
                accI[tile] = __builtin_amdgcn_mfma_f32_16x16x32_bf16(aIH,  bRH, accI[tile], 0,0,0);
                accI[tile] = __builtin_amdgcn_mfma_f32_16x16x32_bf16(aIL,  bRH, accI[tile], 0,0,0);
                accI[tile] = __builtin_amdgcn_mfma_f32_16x16x32_bf16(aIH,  bRL, accI[tile], 0,0,0);
            }
        } else {
            #pragma unroll
            for (int tile = 0; tile < 4; ++tile) {
                const int bb = (tile*16 + lr)*PROW + g*8;
                bf16x8 bRH = *(const bf16x8*)&LBrh[bb];
                bf16x8 bIH = *(const bf16x8*)&LBih[bb];
                accR[tile] = __builtin_amdgcn_mfma_f32_16x16x32_bf16(aRH,  bRH, accR[tile], 0,0,0);
                accR[tile] = __builtin_amdgcn_mfma_f32_16x16x32_bf16(aIHn, bIH, accR[tile], 0,0,0);
                accI[tile] = __builtin_amdgcn_mfma_f32_16x16x32_bf16(aRH,  bIH, accI[tile], 0,0,0);
                accI[tile] = __builtin_amdgcn_mfma_f32_16x16x32_bf16(aIH,  bRH, accI[tile], 0,0,0);
            }
        }
    }

    // ---- epilogue ----
    const float2* b2 = (const float2*)b;
    if (full) {
        // Q plane pre-scaled by 1/sqrt(32) (fold softmax scale into scores)
        const float osc = (z == 0) ? 0.17677669529663687f : 1.0f;
        unsigned short* pr = ws + (z == 0 ? 0 : 2) * (size_t)PLANE_U;
        unsigned short* pi = pr + PLANE_U;
        const int obase = o0 + wave*16 + g*4;
        const int h = obase >> 5, d0 = obase & 31;
        float bR[4], bI[4];
        #pragma unroll
        for (int r = 0; r < 4; ++r) { float2 bb = b2[obase + r]; bR[r] = bb.x; bI[r] = bb.y; }
        #pragma unroll
        for (int tile = 0; tile < 4; ++tile) {
            int s = s0 + tile*16 + lr;
            size_t idx = ((size_t)h*S_LEN + s)*HD + d0;
            ushort4 pkR, pkI;
            pkR.x = f2b((accR[tile][0]+bR[0])*osc); pkR.y = f2b((accR[tile][1]+bR[1])*osc);
            pkR.z = f2b((accR[tile][2]+bR[2])*osc); pkR.w = f2b((accR[tile][3]+bR[3])*osc);
            pkI.x = f2b((accI[tile][0]+bI[0])*osc); pkI.y = f2b((accI[tile][1]+bI[1])*osc);
            pkI.z = f2b((accI[tile][2]+bI[2])*osc); pkI.w = f2b((accI[tile][3]+bI[3])*osc);
            *(ushort4*)&pr[idx] = pkR;
            *(ushort4*)&pi[idx] = pkI;
        }
    } else {
        unsigned short* tr = ws + 4 * (size_t)PLANE_U;
        unsigned short* ti = tr + PLANE_U;
        // key s = s0 + wave*16 + g*4 + r  ->  permuted column
        // c = s0 + (wave>>1)*32 + g*8 + (wave&1)*4 + r  (bijective in [0,64))
        const int cbase = s0 + (wave >> 1)*32 + g*8 + (wave & 1)*4;
        #pragma unroll
        for (int tile = 0; tile < 4; ++tile) {
            int o = o0 + tile*16 + lr;
            int h = o >> 5, d = o & 31;
            float2 bb = b2[o];
            size_t idx = ((size_t)h*HD + d)*S_LEN + cbase;
            ushort4 pkR, pkI;
            pkR.x = f2b(accR[tile][0]+bb.x); pkR.y = f2b(accR[tile][1]+bb.x);
            pkR.z = f2b(accR[tile][2]+bb.x); pkR.w = f2b(accR[tile][3]+bb.x);
            pkI.x = f2b(accI[tile][0]+bb.y); pkI.y = f2b(accI[tile][1]+bb.y);
            pkI.z = f2b(accI[tile][2]+bb.y); pkI.w = f2b(accI[tile][3]+bb.y);
            *(ushort4*)&tr[idx] = pkR;
            *(ushort4*)&ti[idx] = pkI;
        }
    }
}

// ---------------- MFMA flash attention, split-K + 2 q-strips/wave --------
// Swapped QK^T: S = mfma(K,Q) -> lane (g,lr) holds S[key=u*16+g*4+r][q=lr].
// Swapped PV:   O^T = mfma(V^T, P), V^T c-permuted -> P stays in registers.
// NO LDS in the main loop. Q plane pre-scaled by 1/sqrt(32). Combine is
// two-stage into a [4][16][33]-padded region (row stride 264B -> conflict-
// free; l lives in pad slot 32). min-waves stays 4 (8 spilled, round 4).
#define RROW 33                      // padded row stride in float2

__global__ __launch_bounds__(512, 4)
void attn_mfma(const unsigned short* __restrict__ ws, float* __restrict__ out)
{
    const int bid   = blockIdx.x;       // 64 pairs x 16 heads
    const int h     = bid & (NH - 1);   // bid%8 = head%8 -> per-XCD KV locality
    const int pair  = bid >> 4;         // 0..63
    const int wave  = threadIdx.x >> 6; // 0..7 -> k-range owner
    const int lr    = threadIdx.x & 15;
    const int g     = (threadIdx.x & 63) >> 4;

    const unsigned short* qr  = ws + 0*(size_t)PLANE_U + (size_t)h*S_LEN*HD;
    const unsigned short* qi  = ws + 1*(size_t)PLANE_U + (size_t)h*S_LEN*HD;
    const unsigned short* kr  = ws + 2*(size_t)PLANE_U + (size_t)h*S_LEN*HD;
    const unsigned short* ki  = ws + 3*(size_t)PLANE_U + (size_t)h*S_LEN*HD;
    const unsigned short* vtr = ws + 4*(size_t)PLANE_U + (size_t)h*HD*S_LEN;
    const unsigned short* vti = ws + 5*(size_t)PLANE_U + (size_t)h*HD*S_LEN;

    const int qA = pair * 32;           // strip A rows qA..qA+15
    const int qB = qA + 16;             // strip B rows qB..qB+15

    // Q fragments (B-operand of QK): lane supplies Q[q=lr][k=g*8+j]
    bf16x8 bQrA = *(const bf16x8*)&qr[(size_t)(qA + lr)*HD + g*8];
    bf16x8 bQiA = *(const bf16x8*)&qi[(size_t)(qA + lr)*HD + g*8];
    bf16x8 bQrB = *(const bf16x8*)&qr[(size_t)(qB + lr)*HD + g*8];
    bf16x8 bQiB = *(const bf16x8*)&qi[(size_t)(qB + lr)*HD + g*8];
    bf16x8 bQrnA, bQrnB;
    #pragma unroll
    for (int j = 0; j < 8; ++j) {
        bQrnA[j] = bQrA[j] ^ (short)0x8000;
        bQrnB[j] = bQrB[j] ^ (short)0x8000;
    }

    // LDS only for the end-of-kernel two-stage combine: [4][16][33] float2
    __shared__ __align__(16) float2 red[4*16*RROW];

    const f32x4 zf = {0.f, 0.f, 0.f, 0.f};
    f32x4 accA[2][2], accB[2][2];       // [d-tile][0=real,1=imag]
    #pragma unroll
    for (int dt = 0; dt < 2; ++dt) {
        accA[dt][0] = zf; accA[dt][1] = zf;
        accB[dt][0] = zf; accB[dt][1] = zf;
    }
    float lA = 0.f, lB = 0.f;           // denom partials for q=lr

    const int kbeg = wave * 256;
    #pragma unroll 2
    for (int k0 = kbeg; k0 < kbeg + 256; k0 += 32) {
        // ---- one 32-key group: 16 QK mfma (2 strips) -> softmax -> 8 PV --
        bf16x8 bPA, bPB;                // P packed as PV B-fragments
        #pragma unroll
        for (int u = 0; u < 2; ++u) {
            const size_t krow = (size_t)(k0 + u*16 + lr)*HD + g*8;
            bf16x8 aKr = *(const bf16x8*)&kr[krow];
            bf16x8 aKi = *(const bf16x8*)&ki[krow];
            // strip A: re = kr.qr + ki.qi ; im = kr.qi + ki.(-qr)
            {
                f32x4 sR = __builtin_amdgcn_mfma_f32_16x16x32_bf16(aKi, bQiA,  zf, 0, 0, 0);
                sR       = __builtin_amdgcn_mfma_f32_16x16x32_bf16(aKr, bQrA,  sR, 0, 0, 0);
                f32x4 sI = __builtin_amdgcn_mfma_f32_16x16x32_bf16(aKi, bQrnA, zf, 0, 0, 0);
                sI       = __builtin_amdgcn_mfma_f32_16x16x32_bf16(aKr, bQiA,  sI, 0, 0, 0);
                #pragma unroll
                for (int r = 0; r < 4; ++r) {
                    float v = __expf(__builtin_amdgcn_sqrtf(
                        fmaf(sR[r], sR[r], sI[r]*sI[r])));
                    bPA[u*4 + r] = (short)f2b(v);
                    lA += v;
                }
            }
            // strip B
            {
                f32x4 sR = __builtin_amdgcn_mfma_f32_16x16x32_bf16(aKi, bQiB,  zf, 0, 0, 0);
                sR       = __builtin_amdgcn_mfma_f32_16x16x32_bf16(aKr, bQrB,  sR, 0, 0, 0);
                f32x4 sI = __builtin_amdgcn_mfma_f32_16x16x32_bf16(aKi, bQrnB, zf, 0, 0, 0);
                sI       = __builtin_amdgcn_mfma_f32_16x16x32_bf16(aKr, bQiB,  sI, 0, 0, 0);
                #pragma unroll
                for (int r = 0; r < 4; ++r) {
                    float v = __expf(__builtin_amdgcn_sqrtf(
                        fmaf(sR[r], sR[r], sI[r]*sI[r])));
                    bPB[u*4 + r] = (short)f2b(v);
                    lB += v;
                }
            }
        }
        // ---- PV: A = V^T (c-permuted plane, 16B loads), B = P in-register
        #pragma unroll
        for (int dt = 0; dt < 2; ++dt) {
            const size_t vrow = (size_t)(dt*16 + lr)*S_LEN + k0 + g*8;
            bf16x8 aVr = *(const bf16x8*)&vtr[vrow];
            bf16x8 aVi = *(const bf16x8*)&vti[vrow];
            accA[dt][0] = __builtin_amdgcn_mfma_f32_16x16x32_bf16(aVr, bPA, accA[dt][0], 0, 0, 0);
            accA[dt][1] = __builtin_amdgcn_mfma_f32_16x16x32_bf16(aVi, bPA, accA[dt][1], 0, 0, 0);
            accB[dt][0] = __builtin_amdgcn_mfma_f32_16x16x32_bf16(aVr, bPB, accB[dt][0], 0, 0, 0);
            accB[dt][1] = __builtin_amdgcn_mfma_f32_16x16x32_bf16(aVi, bPB, accB[dt][1], 0, 0, 0);
        }
    }

    // ---- wave l-reduction: q=lr slices live at lanes lr, lr+16, lr+32, lr+48
    lA += __shfl_xor(lA, 16); lA += __shfl_xor(lA, 32);
    lB += __shfl_xor(lB, 16); lB += __shfl_xor(lB, 32);

    // ---- two-stage block combine ----
    float2* o2 = (float2*)out;
    #pragma unroll
    for (int strip = 0; strip < 2; ++strip) {
        const f32x4 (*acc)[2] = strip ? accB : accA;
        const float  lval     = strip ? lB : lA;
        const int    qbase    = strip ? qB : qA;
        __syncthreads();
        if (wave < 4) {
            // PV D layout: lane (g,lr) holds O[q=lr][d = dt*16 + g*4 + r]
            #pragma unroll
            for (int dt = 0; dt < 2; ++dt)
                #pragma unroll
                for (int r = 0; r < 4; ++r)
                    red[(wave*16 + lr)*RROW + dt*16 + g*4 + r] =
                        make_float2(acc[dt][0][r], acc[dt][1][r]);
            if (g == 0) red[(wave*16 + lr)*RROW + 32].x = lval;
        }
        __syncthreads();
        if (wave >= 4) {
            const int w = wave - 4;
            #pragma unroll
            for (int dt = 0; dt < 2; ++dt)
                #pragma unroll
                for (int r = 0; r < 4; ++r) {
                    int idx = (w*16 + lr)*RROW + dt*16 + g*4 + r;
                    float2 v = red[idx];
                    v.x += acc[dt][0][r]; v.y += acc[dt][1][r];
                    red[idx] = v;
                }
            if (g == 0) red[(w*16 + lr)*RROW + 32].x += lval;
        }
        __syncthreads();
        // thread i sums 4 partials for output element (q = i>>5, d = i&31)
        const int i = threadIdx.x;
        const int q = i >> 5, d = i & 31;
        float sr = 0.f, si = 0.f, sl = 0.f;
        #pragma unroll
        for (int w = 0; w < 4; ++w) {
            float2 v = red[(w*16 + q)*RROW + d];
            sr += v.x; si += v.y;
            sl += red[(w*16 + q)*RROW + 32].x;
        }
        float inv = 1.0f / sl;
        o2[(size_t)(qbase + q)*C_DIM + h*HD + d] = make_float2(sr*inv, si*inv);
    }
}

extern "C" void kernel_launch(void* const* d_in, const int* in_sizes, int n_in,
                              void* d_out, int out_size, void* d_ws, size_t ws_size,
                              hipStream_t stream)
{
    const float* Q  = (const float*)d_in[0];
    const float* V  = (const float*)d_in[1];
    const float* K  = (const float*)d_in[2];
    const float* Wq = (const float*)d_in[3];
    const float* bq = (const float*)d_in[4];
    const float* Wk = (const float*)d_in[5];
    const float* bk = (const float*)d_in[6];
    const float* Wv = (const float*)d_in[7];
    const float* bv = (const float*)d_in[8];
    unsigned short* ws = (unsigned short*)d_ws;   // 6 planes * 2MB = 12MB
    float* out = (float*)d_out;

    dim3 gp(S_LEN/64, C_DIM/64, 3);
    proj_mfma<<<gp, 256, 0, stream>>>(Q, V, K, Wq, bq, Wk, bk, Wv, bv, ws);

    attn_mfma<<<dim3(64*NH), 512, 0, stream>>>(ws, out);
}